// Round 8
// baseline (899.662 us; speedup 1.0000x reference)
//
#include <hip/hip_runtime.h>
#include <cstdint>

// Problem constants (fixed dataset: setup_inputs in reference)
constexpr int B = 8, N = 100000, G = 64, T = 256, TOPK = 27;
constexpr int BN = B * N;
constexpr int CAP = 1536;           // candidate LDS capacity per gt (E[cnt]~172)
constexpr int GPB = 2;              // gts per assign block
constexpr int WL_CAP = 32768;       // 2 assign runs x <=13824 positives
constexpr int FILL_BLOCKS = 2048;   // token_fill grid (grid-stride)
#define NEG_INF_VAL (-100000000.0f) // -INF in reference, exactly representable

typedef float v4f __attribute__((ext_vector_type(4)));

// ---------------------------------------------------------------------------
// Kernel 0: zero best[] and the worklist counter.
// ---------------------------------------------------------------------------
__global__ __launch_bounds__(256) void atss_zero_kernel(
    unsigned long long* __restrict__ best, int* __restrict__ wl_cnt)
{
  int i = blockIdx.x * 256 + threadIdx.x;
  if (i < BN) best[i] = 0ULL;
  if (i == 0) *wl_cnt = 0;
}

// ---------------------------------------------------------------------------
// Kernel A (unchanged from round 7; launched TWICE this round as a timing
// probe — the kernel is idempotent: atomicMax re-applies identical values,
// and duplicate worklist entries are idempotent because the scatter kernel
// re-reads the resolved best[i]).
// ---------------------------------------------------------------------------
__global__ __launch_bounds__(1024) void atss_assign_kernel(
    const float* __restrict__ anchors,     // [B,N,4]
    const float* __restrict__ gts,         // [B,G,4]
    unsigned long long* __restrict__ best, // [B*N]
    int* __restrict__ wl_cnt,
    int* __restrict__ worklist)
{
#pragma clang fp contract(off)
  __shared__ float s_d[GPB][CAP];
  __shared__ int   s_i[GPB][CAP];
  __shared__ int   s_cnt[GPB];
  __shared__ int   s_sel[GPB][TOPK];
  __shared__ float s_iou[GPB][TOPK];
  __shared__ int   s_in[GPB][TOPK];
  __shared__ float s_thresh;

  // XCD-bijective swizzle over 256 blocks: bid%8==k -> XCD k -> batch k.
  const int bid = blockIdx.x;
  const int p   = (bid & 7) * 32 + (bid >> 3);
  const int b   = p >> 5;            // batch
  const int g0  = (p & 31) * 2;      // first gt of this pair within batch
  const int bg0 = b * G + g0;
  const int tid = threadIdx.x;

  const float4 gb0 = ((const float4*)gts)[bg0];
  const float4 gb1 = ((const float4*)gts)[bg0 + 1];
  const float gcx0 = (gb0.z + gb0.x) * 0.5f, gcy0 = (gb0.w + gb0.y) * 0.5f;
  const float gcx1 = (gb1.z + gb1.x) * 0.5f, gcy1 = (gb1.w + gb1.y) * 0.5f;

  const float4* abase = (const float4*)(anchors + (size_t)b * N * 4);

  // --- Candidate collection: all anchors with d^2 < thr^2, per gt. ---
  float thr2_0 = 576.0f, thr2_1 = 576.0f;
  int M0 = -1, M1 = -1; // -1 = unresolved (uniform across threads)
  for (int attempt = 0; attempt < 8 && (M0 < 0 || M1 < 0); ++attempt) {
    if (tid == 0 && M0 < 0) s_cnt[0] = 0;
    if (tid == 1 && M1 < 0) s_cnt[1] = 0;
    __syncthreads();
    const bool a0 = (M0 < 0), a1 = (M1 < 0);

#define ATSS_TEST(ab, idx)                                                    \
  do {                                                                        \
    float cx = ((ab).z + (ab).x) * 0.5f;                                      \
    float cy = ((ab).w + (ab).y) * 0.5f;                                      \
    if (a0) {                                                                 \
      float dx = cx - gcx0, dy = cy - gcy0;                                   \
      float d2 = __fmul_rn(dx, dx) + __fmul_rn(dy, dy);                       \
      if (d2 < thr2_0) {                                                      \
        int q_ = atomicAdd(&s_cnt[0], 1);                                     \
        if (q_ < CAP) { s_d[0][q_] = __fsqrt_rn(d2); s_i[0][q_] = (idx); }    \
      }                                                                       \
    }                                                                         \
    if (a1) {                                                                 \
      float dx = cx - gcx1, dy = cy - gcy1;                                   \
      float d2 = __fmul_rn(dx, dx) + __fmul_rn(dy, dy);                       \
      if (d2 < thr2_1) {                                                      \
        int q_ = atomicAdd(&s_cnt[1], 1);                                     \
        if (q_ < CAP) { s_d[1][q_] = __fsqrt_rn(d2); s_i[1][q_] = (idx); }    \
      }                                                                       \
    }                                                                         \
  } while (0)

    for (int m = tid; m < N / 4; m += 1024) {
      float4 a0b = abase[4 * m];
      float4 a1b = abase[4 * m + 1];
      float4 a2b = abase[4 * m + 2];
      float4 a3b = abase[4 * m + 3];
      ATSS_TEST(a0b, 4 * m);
      ATSS_TEST(a1b, 4 * m + 1);
      ATSS_TEST(a2b, 4 * m + 2);
      ATSS_TEST(a3b, 4 * m + 3);
    }
#undef ATSS_TEST
    __syncthreads();
    const int c0 = s_cnt[0], c1 = s_cnt[1];
    __syncthreads();
    if (M0 < 0) {
      if (c0 >= TOPK && c0 <= CAP) M0 = c0;
      else thr2_0 *= (c0 < TOPK) ? 16.0f : 0.25f;
    }
    if (M1 < 0) {
      if (c1 >= TOPK && c1 <= CAP) M1 = c1;
      else thr2_1 *= (c1 < TOPK) ? 16.0f : 0.25f;
    }
  }

  // --- Per-gt: exact top-27, IoU, threshold, scatter + worklist append. ---
  for (int q = 0; q < GPB; ++q) {
    const int M = (q == 0) ? M0 : M1;
    const float4 gbox = (q == 0) ? gb0 : gb1;
    const int g = g0 + q;

    for (int s = tid; s < M; s += 1024) {
      unsigned long long pk_s =
          ((unsigned long long)__float_as_uint(s_d[q][s]) << 20) |
          (unsigned long long)(unsigned)s_i[q][s];
      int rank = 0;
      for (int j = 0; j < M; ++j) {
        unsigned long long pk_j =
            ((unsigned long long)__float_as_uint(s_d[q][j]) << 20) |
            (unsigned long long)(unsigned)s_i[q][j];
        rank += (pk_j < pk_s) ? 1 : 0;
      }
      if (rank < TOPK) s_sel[q][rank] = s_i[q][s];
    }
    __syncthreads();

    if (tid < TOPK) {
      int a = s_sel[q][tid];
      float4 ab = abase[a];
      float area_a = __fmul_rn(ab.z - ab.x, ab.w - ab.y);
      float area_b = __fmul_rn(gbox.z - gbox.x, gbox.w - gbox.y);
      float ltx = fmaxf(ab.x, gbox.x), lty = fmaxf(ab.y, gbox.y);
      float rbx = fminf(ab.z, gbox.z), rby = fminf(ab.w, gbox.w);
      float w = fmaxf(rbx - ltx, 0.0f), h = fmaxf(rby - lty, 0.0f);
      float inter = __fmul_rn(w, h);
      float uni = (area_a + area_b) - inter;
      s_iou[q][tid] = inter / uni;
      float acx = (ab.z + ab.x) * 0.5f, acy = (ab.w + ab.y) * 0.5f;
      float l = acx - gbox.x, t = acy - gbox.y;
      float r = gbox.z - acx, bt = gbox.w - acy;
      float mn = fminf(fminf(l, t), fminf(r, bt));
      s_in[q][tid] = (mn > 0.01f) ? 1 : 0;
    }
    __syncthreads();

    if (tid == 0) {
      float sum = 0.0f;
      for (int k = 0; k < TOPK; ++k) sum += s_iou[q][k];
      float mean = sum / (float)TOPK;
      float vs = 0.0f;
      for (int k = 0; k < TOPK; ++k) {
        float d = s_iou[q][k] - mean;
        vs += __fmul_rn(d, d);
      }
      float sd = __fsqrt_rn(vs / (float)(TOPK - 1));
      s_thresh = mean + sd;
    }
    __syncthreads();

    // Scatter positives into best[] and append to the scatter worklist
    // (wave-aggregated: one atomicAdd per (block,q)).
    if (tid < TOPK) {
      float iou = s_iou[q][tid];
      bool pos = s_in[q][tid] && (iou >= s_thresh);
      if (pos) {
        unsigned long long pk =
            ((unsigned long long)__float_as_uint(iou) << 32) |
            (unsigned long long)(0xFFFFFFFFu - (unsigned)g);
        atomicMax(&best[(size_t)b * N + s_sel[q][tid]], pk);
      }
      unsigned long long mask = __ballot(pos);
      int nact = __popcll(mask);
      int base = 0;
      if (tid == 0 && nact > 0) base = atomicAdd(wl_cnt, nact);
      base = __shfl(base, 0);
      if (pos) {
        int rank = __popcll(mask & ((1ULL << tid) - 1ULL));
        worklist[base + rank] = b * N + s_sel[q][tid];
      }
    }
    __syncthreads(); // s_thresh reused by next q
  }
}

// ---------------------------------------------------------------------------
// Kernel W1: val / idx / matched_gts. One thread per anchor, fully coalesced.
// ---------------------------------------------------------------------------
__global__ __launch_bounds__(256) void atss_scalar_write_kernel(
    const unsigned long long* __restrict__ best, // [B*N]
    const float* __restrict__ gts,               // [B,G,4]
    float* __restrict__ out)
{
  float* __restrict__ out_val = out;
  float* __restrict__ out_idx = out + (size_t)BN;
  float* __restrict__ out_mg  = out + (size_t)2 * BN;

  const int i = blockIdx.x * 256 + threadIdx.x;
  unsigned long long p = best[i];
  const int b_ = i / N;
  int g = 0;
  float val = NEG_INF_VAL;
  if (p != 0ULL) {
    g   = (int)(0xFFFFFFFFu - (unsigned)(p & 0xFFFFFFFFULL));
    val = __uint_as_float((unsigned)(p >> 32));
  }
  const int row = b_ * G + g; // unmatched -> g=0 (matches argmax of all -INF)
  out_val[i] = val;
  out_idx[i] = (float)g;
  ((v4f*)out_mg)[i] = ((const v4f*)gts)[row];
}

// ---------------------------------------------------------------------------
// Kernel F: token fill. Writes the unmatched one-hot pattern to ALL token
// rows (fill-structured, at the store floor). Matched rows (~3%) are
// overwritten by the scatter kernel afterwards.
// ---------------------------------------------------------------------------
__global__ __launch_bounds__(256) void atss_token_fill_kernel(
    float* __restrict__ out)
{
  v4f* __restrict__ tok = (v4f*)(out + (size_t)6 * BN);
  const int NT = FILL_BLOCKS * 256;                 // threads in grid
  const int total = BN * (T / 4);                   // 51.2M v4f
  for (int j = blockIdx.x * 256 + threadIdx.x; j < total; j += NT) {
    v4f t = (v4f){0.0f, 0.0f, 0.0f, ((j & 63) == 63) ? 1.0f : 0.0f};
    tok[j] = t;
  }
}

// ---------------------------------------------------------------------------
// Kernel S: token scatter. One wave per worklist entry: re-read best[i]
// (resolved winner; makes duplicate worklist entries idempotent), copy the
// 1 KB token row over the fill.
// ---------------------------------------------------------------------------
__global__ __launch_bounds__(256) void atss_token_scatter_kernel(
    const unsigned long long* __restrict__ best, // [B*N]
    const int* __restrict__ wl_cnt,
    const int* __restrict__ worklist,
    const float* __restrict__ tokens,            // [B,G,T]
    float* __restrict__ out)
{
  const int w = blockIdx.x * 4 + (threadIdx.x >> 6); // global wave id
  const int lane = threadIdx.x & 63;
  const int cnt = *wl_cnt;
  if (w >= cnt) return;
  const int i = worklist[w];
  const unsigned long long p = best[i];            // positive -> p != 0
  const int b_ = i / N;
  const int g  = (int)(0xFFFFFFFFu - (unsigned)(p & 0xFFFFFFFFULL));
  v4f t = ((const v4f*)tokens)[(size_t)(b_ * G + g) * 64 + lane];
  ((v4f*)(out + (size_t)6 * BN + (size_t)i * T))[lane] = t;
}

extern "C" void kernel_launch(void* const* d_in, const int* in_sizes, int n_in,
                              void* d_out, int out_size, void* d_ws, size_t ws_size,
                              hipStream_t stream) {
  const float* anchors = (const float*)d_in[0]; // [B,N,4]
  const float* gts     = (const float*)d_in[1]; // [B,G,4]
  const float* tokens  = (const float*)d_in[2]; // [B,G,T]
  float* out = (float*)d_out;

  // Workspace: best (6.4 MB) | wl_cnt (4 B, padded to 64 B) | worklist (128 KB)
  unsigned long long* best = (unsigned long long*)d_ws;
  int* wl_cnt   = (int*)((char*)d_ws + sizeof(unsigned long long) * (size_t)BN);
  int* worklist = wl_cnt + 16;

  atss_zero_kernel<<<(BN + 255) / 256, 256, 0, stream>>>(best, wl_cnt);
  // TIMING PROBE: assign launched twice (idempotent). dur_us delta vs round 7
  // == warm assign cost. Readout pre-committed in the journal:
  //   delta <= 30us -> assign small -> residual is harness overhead -> roofline.
  //   delta >= 80us -> assign is the hidden consumer -> restructure assign.
  atss_assign_kernel<<<B * G / GPB, 1024, 0, stream>>>(anchors, gts, best,
                                                       wl_cnt, worklist);
  atss_assign_kernel<<<B * G / GPB, 1024, 0, stream>>>(anchors, gts, best,
                                                       wl_cnt, worklist);
  atss_scalar_write_kernel<<<BN / 256, 256, 0, stream>>>(best, gts, out);
  atss_token_fill_kernel<<<FILL_BLOCKS, 256, 0, stream>>>(out);
  atss_token_scatter_kernel<<<(WL_CAP + 1023) / 1024 * 256, 256, 0, stream>>>(
      best, wl_cnt, worklist, tokens, out);
}

// Round 9
// 862.745 us; speedup vs baseline: 1.0428x; 1.0428x over previous
//
#include <hip/hip_runtime.h>
#include <cstdint>

// Problem constants (fixed dataset: setup_inputs in reference)
constexpr int B = 8, N = 100000, G = 64, T = 256, TOPK = 27;
constexpr int BN = B * N;
constexpr int CAP = 1536;           // candidate LDS capacity per gt (E[cnt]~172)
constexpr int GPB = 2;              // gts per assign block
constexpr int WL_CAP = 16384;       // >= B*G*TOPK = 13824 max positives
constexpr int FILL_BLOCKS = 2048;   // fill grid (grid-stride)
#define NEG_INF_VAL (-100000000.0f) // -INF in reference, exactly representable

typedef float v4f __attribute__((ext_vector_type(4)));

// ---------------------------------------------------------------------------
// Kernel F0: fused init. (a) zero best[] and the worklist counter; (b) write
// the unmatched one-hot pattern to ALL token rows (fill-structured, at the
// store floor -- proven write-parity with the read+select writer in r7).
// Runs BEFORE assign: legal because matched token rows are only produced by
// the scatter kernel, which runs last.
// ---------------------------------------------------------------------------
__global__ __launch_bounds__(256) void atss_fillzero_kernel(
    unsigned long long* __restrict__ best, int* __restrict__ wl_cnt,
    float* __restrict__ out)
{
  const int t0 = blockIdx.x * 256 + threadIdx.x;
  const int NT = FILL_BLOCKS * 256;
  if (t0 == 0) *wl_cnt = 0;
  for (int i = t0; i < BN; i += NT) best[i] = 0ULL;

  v4f* __restrict__ tok = (v4f*)(out + (size_t)6 * BN);
  const int total = BN * (T / 4); // 51.2M v4f
  for (int j = t0; j < total; j += NT) {
    v4f t = (v4f){0.0f, 0.0f, 0.0f, ((j & 63) == 63) ? 1.0f : 0.0f};
    tok[j] = t;
  }
}

// ---------------------------------------------------------------------------
// Kernel A: 2 gts per block (256 blocks x 1024 threads). Scans the batch's
// anchors once, computes centers inline (bit-identical (z+x)*0.5f formula),
// tests vs both gts. Per-gt candidate sets, exact top-27 by rank counting
// over (d, idx) keys (insertion-order independent), IoU + mean/unbiased-std
// threshold + center-inside, packed atomicMax scatter into best[], and a
// wave-aggregated worklist append of every positive's global anchor index.
// Measured (r8 duplication probe): ~38 us warm.
// packed best = (f32bits(iou) << 32) | (0xFFFFFFFF - g)
//   -> max = largest iou; tie -> smallest g (matches jnp.argmax first-max).
// packed == 0 means "unmatched" (positives always have iou > 0).
// ---------------------------------------------------------------------------
__global__ __launch_bounds__(1024) void atss_assign_kernel(
    const float* __restrict__ anchors,     // [B,N,4]
    const float* __restrict__ gts,         // [B,G,4]
    unsigned long long* __restrict__ best, // [B*N]
    int* __restrict__ wl_cnt,
    int* __restrict__ worklist)
{
#pragma clang fp contract(off)
  __shared__ float s_d[GPB][CAP];
  __shared__ int   s_i[GPB][CAP];
  __shared__ int   s_cnt[GPB];
  __shared__ int   s_sel[GPB][TOPK];
  __shared__ float s_iou[GPB][TOPK];
  __shared__ int   s_in[GPB][TOPK];
  __shared__ float s_thresh;

  // XCD-bijective swizzle over 256 blocks: bid%8==k -> XCD k -> batch k.
  const int bid = blockIdx.x;
  const int p   = (bid & 7) * 32 + (bid >> 3);
  const int b   = p >> 5;            // batch
  const int g0  = (p & 31) * 2;      // first gt of this pair within batch
  const int bg0 = b * G + g0;
  const int tid = threadIdx.x;

  const float4 gb0 = ((const float4*)gts)[bg0];
  const float4 gb1 = ((const float4*)gts)[bg0 + 1];
  const float gcx0 = (gb0.z + gb0.x) * 0.5f, gcy0 = (gb0.w + gb0.y) * 0.5f;
  const float gcx1 = (gb1.z + gb1.x) * 0.5f, gcy1 = (gb1.w + gb1.y) * 0.5f;

  const float4* abase = (const float4*)(anchors + (size_t)b * N * 4);

  // --- Candidate collection: all anchors with d^2 < thr^2, per gt. ---
  float thr2_0 = 576.0f, thr2_1 = 576.0f;
  int M0 = -1, M1 = -1; // -1 = unresolved (uniform across threads)
  for (int attempt = 0; attempt < 8 && (M0 < 0 || M1 < 0); ++attempt) {
    if (tid == 0 && M0 < 0) s_cnt[0] = 0;
    if (tid == 1 && M1 < 0) s_cnt[1] = 0;
    __syncthreads();
    const bool a0 = (M0 < 0), a1 = (M1 < 0);

#define ATSS_TEST(ab, idx)                                                    \
  do {                                                                        \
    float cx = ((ab).z + (ab).x) * 0.5f;                                      \
    float cy = ((ab).w + (ab).y) * 0.5f;                                      \
    if (a0) {                                                                 \
      float dx = cx - gcx0, dy = cy - gcy0;                                   \
      float d2 = __fmul_rn(dx, dx) + __fmul_rn(dy, dy);                       \
      if (d2 < thr2_0) {                                                      \
        int q_ = atomicAdd(&s_cnt[0], 1);                                     \
        if (q_ < CAP) { s_d[0][q_] = __fsqrt_rn(d2); s_i[0][q_] = (idx); }    \
      }                                                                       \
    }                                                                         \
    if (a1) {                                                                 \
      float dx = cx - gcx1, dy = cy - gcy1;                                   \
      float d2 = __fmul_rn(dx, dx) + __fmul_rn(dy, dy);                       \
      if (d2 < thr2_1) {                                                      \
        int q_ = atomicAdd(&s_cnt[1], 1);                                     \
        if (q_ < CAP) { s_d[1][q_] = __fsqrt_rn(d2); s_i[1][q_] = (idx); }    \
      }                                                                       \
    }                                                                         \
  } while (0)

    for (int m = tid; m < N / 4; m += 1024) {
      float4 a0b = abase[4 * m];
      float4 a1b = abase[4 * m + 1];
      float4 a2b = abase[4 * m + 2];
      float4 a3b = abase[4 * m + 3];
      ATSS_TEST(a0b, 4 * m);
      ATSS_TEST(a1b, 4 * m + 1);
      ATSS_TEST(a2b, 4 * m + 2);
      ATSS_TEST(a3b, 4 * m + 3);
    }
#undef ATSS_TEST
    __syncthreads();
    const int c0 = s_cnt[0], c1 = s_cnt[1];
    __syncthreads();
    if (M0 < 0) {
      if (c0 >= TOPK && c0 <= CAP) M0 = c0;
      else thr2_0 *= (c0 < TOPK) ? 16.0f : 0.25f;
    }
    if (M1 < 0) {
      if (c1 >= TOPK && c1 <= CAP) M1 = c1;
      else thr2_1 *= (c1 < TOPK) ? 16.0f : 0.25f;
    }
  }

  // --- Per-gt: exact top-27, IoU, threshold, scatter + worklist append. ---
  for (int q = 0; q < GPB; ++q) {
    const int M = (q == 0) ? M0 : M1;
    const float4 gbox = (q == 0) ? gb0 : gb1;
    const int g = g0 + q;

    for (int s = tid; s < M; s += 1024) {
      unsigned long long pk_s =
          ((unsigned long long)__float_as_uint(s_d[q][s]) << 20) |
          (unsigned long long)(unsigned)s_i[q][s];
      int rank = 0;
      for (int j = 0; j < M; ++j) {
        unsigned long long pk_j =
            ((unsigned long long)__float_as_uint(s_d[q][j]) << 20) |
            (unsigned long long)(unsigned)s_i[q][j];
        rank += (pk_j < pk_s) ? 1 : 0;
      }
      if (rank < TOPK) s_sel[q][rank] = s_i[q][s];
    }
    __syncthreads();

    if (tid < TOPK) {
      int a = s_sel[q][tid];
      float4 ab = abase[a];
      float area_a = __fmul_rn(ab.z - ab.x, ab.w - ab.y);
      float area_b = __fmul_rn(gbox.z - gbox.x, gbox.w - gbox.y);
      float ltx = fmaxf(ab.x, gbox.x), lty = fmaxf(ab.y, gbox.y);
      float rbx = fminf(ab.z, gbox.z), rby = fminf(ab.w, gbox.w);
      float w = fmaxf(rbx - ltx, 0.0f), h = fmaxf(rby - lty, 0.0f);
      float inter = __fmul_rn(w, h);
      float uni = (area_a + area_b) - inter;
      s_iou[q][tid] = inter / uni;
      float acx = (ab.z + ab.x) * 0.5f, acy = (ab.w + ab.y) * 0.5f;
      float l = acx - gbox.x, t = acy - gbox.y;
      float r = gbox.z - acx, bt = gbox.w - acy;
      float mn = fminf(fminf(l, t), fminf(r, bt));
      s_in[q][tid] = (mn > 0.01f) ? 1 : 0;
    }
    __syncthreads();

    if (tid == 0) {
      float sum = 0.0f;
      for (int k = 0; k < TOPK; ++k) sum += s_iou[q][k];
      float mean = sum / (float)TOPK;
      float vs = 0.0f;
      for (int k = 0; k < TOPK; ++k) {
        float d = s_iou[q][k] - mean;
        vs += __fmul_rn(d, d);
      }
      float sd = __fsqrt_rn(vs / (float)(TOPK - 1));
      s_thresh = mean + sd;
    }
    __syncthreads();

    // Scatter positives into best[] and append to the scatter worklist
    // (wave-aggregated: one atomicAdd per (block,q)).
    if (tid < TOPK) {
      float iou = s_iou[q][tid];
      bool pos = s_in[q][tid] && (iou >= s_thresh);
      if (pos) {
        unsigned long long pk =
            ((unsigned long long)__float_as_uint(iou) << 32) |
            (unsigned long long)(0xFFFFFFFFu - (unsigned)g);
        atomicMax(&best[(size_t)b * N + s_sel[q][tid]], pk);
      }
      unsigned long long mask = __ballot(pos);
      int nact = __popcll(mask);
      int base = 0;
      if (tid == 0 && nact > 0) base = atomicAdd(wl_cnt, nact);
      base = __shfl(base, 0);
      if (pos) {
        int rank = __popcll(mask & ((1ULL << tid) - 1ULL));
        worklist[base + rank] = b * N + s_sel[q][tid];
      }
    }
    __syncthreads(); // s_thresh reused by next q
  }
}

// ---------------------------------------------------------------------------
// Kernel W1: val / idx / matched_gts. One thread per anchor, fully coalesced.
// ---------------------------------------------------------------------------
__global__ __launch_bounds__(256) void atss_scalar_write_kernel(
    const unsigned long long* __restrict__ best, // [B*N]
    const float* __restrict__ gts,               // [B,G,4]
    float* __restrict__ out)
{
  float* __restrict__ out_val = out;
  float* __restrict__ out_idx = out + (size_t)BN;
  float* __restrict__ out_mg  = out + (size_t)2 * BN;

  const int i = blockIdx.x * 256 + threadIdx.x;
  unsigned long long p = best[i];
  const int b_ = i / N;
  int g = 0;
  float val = NEG_INF_VAL;
  if (p != 0ULL) {
    g   = (int)(0xFFFFFFFFu - (unsigned)(p & 0xFFFFFFFFULL));
    val = __uint_as_float((unsigned)(p >> 32));
  }
  const int row = b_ * G + g; // unmatched -> g=0 (matches argmax of all -INF)
  out_val[i] = val;
  out_idx[i] = (float)g;
  ((v4f*)out_mg)[i] = ((const v4f*)gts)[row];
}

// ---------------------------------------------------------------------------
// Kernel S: token scatter. One wave per worklist entry (<= 13824 positives):
// re-read best[i] (resolved winner; makes duplicate worklist entries
// idempotent), copy the 1 KB token row over the fill.
// ---------------------------------------------------------------------------
__global__ __launch_bounds__(256) void atss_token_scatter_kernel(
    const unsigned long long* __restrict__ best, // [B*N]
    const int* __restrict__ wl_cnt,
    const int* __restrict__ worklist,
    const float* __restrict__ tokens,            // [B,G,T]
    float* __restrict__ out)
{
  const int w = blockIdx.x * 4 + (threadIdx.x >> 6); // global wave id
  const int lane = threadIdx.x & 63;
  const int cnt = *wl_cnt;
  if (w >= cnt) return;
  const int i = worklist[w];
  const unsigned long long p = best[i];            // positive -> p != 0
  const int b_ = i / N;
  const int g  = (int)(0xFFFFFFFFu - (unsigned)(p & 0xFFFFFFFFULL));
  v4f t = ((const v4f*)tokens)[(size_t)(b_ * G + g) * 64 + lane];
  ((v4f*)(out + (size_t)6 * BN + (size_t)i * T))[lane] = t;
}

extern "C" void kernel_launch(void* const* d_in, const int* in_sizes, int n_in,
                              void* d_out, int out_size, void* d_ws, size_t ws_size,
                              hipStream_t stream) {
  const float* anchors = (const float*)d_in[0]; // [B,N,4]
  const float* gts     = (const float*)d_in[1]; // [B,G,4]
  const float* tokens  = (const float*)d_in[2]; // [B,G,T]
  float* out = (float*)d_out;

  // Workspace: best (6.4 MB) | wl_cnt (4 B, padded to 64 B) | worklist (64 KB)
  unsigned long long* best = (unsigned long long*)d_ws;
  int* wl_cnt   = (int*)((char*)d_ws + sizeof(unsigned long long) * (size_t)BN);
  int* worklist = wl_cnt + 16;

  atss_fillzero_kernel<<<FILL_BLOCKS, 256, 0, stream>>>(best, wl_cnt, out);
  atss_assign_kernel<<<B * G / GPB, 1024, 0, stream>>>(anchors, gts, best,
                                                       wl_cnt, worklist);
  atss_scalar_write_kernel<<<BN / 256, 256, 0, stream>>>(best, gts, out);
  atss_token_scatter_kernel<<<(WL_CAP + 1023) / 1024 * 256, 256, 0, stream>>>(
      best, wl_cnt, worklist, tokens, out);
}

// Round 10
// 855.397 us; speedup vs baseline: 1.0517x; 1.0086x over previous
//
#include <hip/hip_runtime.h>
#include <cstdint>

// Problem constants (fixed dataset: setup_inputs in reference)
constexpr int B = 8, N = 100000, G = 64, T = 256, TOPK = 27;
constexpr int BN = B * N;
constexpr int CAP = 1536;           // candidate LDS capacity per gt (E[cnt]~172)
constexpr int GPB = 2;              // gts per assign block
constexpr int WL_CAP = 16384;       // >= B*G*TOPK = 13824 max positives
constexpr int ASSIGN_BLOCKS = B * G / GPB;   // 256
constexpr int FAT_BLOCKS = 1024;             // 256 assign + 768 fill
constexpr int W1_BLOCKS = BN / 256;          // 3125
constexpr int SC_BLOCKS = WL_CAP / 4;        // 4096 (4 waves/block)
#define NEG_INF_VAL (-100000000.0f) // -INF in reference, exactly representable

typedef float v4f __attribute__((ext_vector_type(4)));

// ---------------------------------------------------------------------------
// Kernel Z: zero best[] + worklist counter. Must fully precede the fat
// kernel's atomicMax ops -> separate dispatch (stream-ordered). ~3 us.
// ---------------------------------------------------------------------------
__global__ __launch_bounds__(256) void atss_zero_kernel(
    unsigned long long* __restrict__ best, int* __restrict__ wl_cnt)
{
  const int t0 = blockIdx.x * 256 + threadIdx.x;
  if (t0 == 0) *wl_cnt = 0;
  for (int i = t0; i < BN; i += 512 * 256) best[i] = 0ULL;
}

// ---------------------------------------------------------------------------
// Kernel FAT: blocks [0,256) = assign (unchanged r9 body, ~38 us, L2/LDS-
// bound); blocks [256,1024) = token fill (819 MB unmatched one-hot pattern,
// ~132 us, store-BW-bound). The two halves write disjoint memory (best/
// worklist vs out_tok) -> no intra-kernel ordering needed; overlapping them
// hides assign under the fill (serial 132+38 -> concurrent ~max).
// Matched token rows (~3%) are overwritten by the scatter half of W afterwards.
// packed best = (f32bits(iou) << 32) | (0xFFFFFFFF - g)
//   -> max = largest iou; tie -> smallest g (matches jnp.argmax first-max).
// packed == 0 means "unmatched" (positives always have iou > 0).
// ---------------------------------------------------------------------------
__global__ __launch_bounds__(1024) void atss_fat_kernel(
    const float* __restrict__ anchors,     // [B,N,4]
    const float* __restrict__ gts,         // [B,G,4]
    unsigned long long* __restrict__ best, // [B*N]
    int* __restrict__ wl_cnt,
    int* __restrict__ worklist,
    float* __restrict__ out)
{
#pragma clang fp contract(off)
  __shared__ float s_d[GPB][CAP];
  __shared__ int   s_i[GPB][CAP];
  __shared__ int   s_cnt[GPB];
  __shared__ int   s_sel[GPB][TOPK];
  __shared__ float s_iou[GPB][TOPK];
  __shared__ int   s_in[GPB][TOPK];
  __shared__ float s_thresh;

  const int bid = blockIdx.x;
  const int tid = threadIdx.x;

  if (bid >= ASSIGN_BLOCKS) {
    // ---------------- Token fill half ----------------
    const int fb  = bid - ASSIGN_BLOCKS;
    const int NFT = (FAT_BLOCKS - ASSIGN_BLOCKS) * 1024;
    v4f* __restrict__ tok = (v4f*)(out + (size_t)6 * BN);
    const int total = BN * (T / 4); // 51.2M v4f
    for (int j = fb * 1024 + tid; j < total; j += NFT) {
      v4f t = (v4f){0.0f, 0.0f, 0.0f, ((j & 63) == 63) ? 1.0f : 0.0f};
      tok[j] = t;
    }
    return;
  }

  // ---------------- Assign half (identical to r9) ----------------
  // XCD-bijective swizzle over 256 blocks: bid%8==k -> XCD k -> batch k.
  const int p   = (bid & 7) * 32 + (bid >> 3);
  const int b   = p >> 5;            // batch
  const int g0  = (p & 31) * 2;      // first gt of this pair within batch
  const int bg0 = b * G + g0;

  const float4 gb0 = ((const float4*)gts)[bg0];
  const float4 gb1 = ((const float4*)gts)[bg0 + 1];
  const float gcx0 = (gb0.z + gb0.x) * 0.5f, gcy0 = (gb0.w + gb0.y) * 0.5f;
  const float gcx1 = (gb1.z + gb1.x) * 0.5f, gcy1 = (gb1.w + gb1.y) * 0.5f;

  const float4* abase = (const float4*)(anchors + (size_t)b * N * 4);

  // --- Candidate collection: all anchors with d^2 < thr^2, per gt. ---
  float thr2_0 = 576.0f, thr2_1 = 576.0f;
  int M0 = -1, M1 = -1; // -1 = unresolved (uniform across threads)
  for (int attempt = 0; attempt < 8 && (M0 < 0 || M1 < 0); ++attempt) {
    if (tid == 0 && M0 < 0) s_cnt[0] = 0;
    if (tid == 1 && M1 < 0) s_cnt[1] = 0;
    __syncthreads();
    const bool a0 = (M0 < 0), a1 = (M1 < 0);

#define ATSS_TEST(ab, idx)                                                    \
  do {                                                                        \
    float cx = ((ab).z + (ab).x) * 0.5f;                                      \
    float cy = ((ab).w + (ab).y) * 0.5f;                                      \
    if (a0) {                                                                 \
      float dx = cx - gcx0, dy = cy - gcy0;                                   \
      float d2 = __fmul_rn(dx, dx) + __fmul_rn(dy, dy);                       \
      if (d2 < thr2_0) {                                                      \
        int q_ = atomicAdd(&s_cnt[0], 1);                                     \
        if (q_ < CAP) { s_d[0][q_] = __fsqrt_rn(d2); s_i[0][q_] = (idx); }    \
      }                                                                       \
    }                                                                         \
    if (a1) {                                                                 \
      float dx = cx - gcx1, dy = cy - gcy1;                                   \
      float d2 = __fmul_rn(dx, dx) + __fmul_rn(dy, dy);                       \
      if (d2 < thr2_1) {                                                      \
        int q_ = atomicAdd(&s_cnt[1], 1);                                     \
        if (q_ < CAP) { s_d[1][q_] = __fsqrt_rn(d2); s_i[1][q_] = (idx); }    \
      }                                                                       \
    }                                                                         \
  } while (0)

    for (int m = tid; m < N / 4; m += 1024) {
      float4 a0b = abase[4 * m];
      float4 a1b = abase[4 * m + 1];
      float4 a2b = abase[4 * m + 2];
      float4 a3b = abase[4 * m + 3];
      ATSS_TEST(a0b, 4 * m);
      ATSS_TEST(a1b, 4 * m + 1);
      ATSS_TEST(a2b, 4 * m + 2);
      ATSS_TEST(a3b, 4 * m + 3);
    }
#undef ATSS_TEST
    __syncthreads();
    const int c0 = s_cnt[0], c1 = s_cnt[1];
    __syncthreads();
    if (M0 < 0) {
      if (c0 >= TOPK && c0 <= CAP) M0 = c0;
      else thr2_0 *= (c0 < TOPK) ? 16.0f : 0.25f;
    }
    if (M1 < 0) {
      if (c1 >= TOPK && c1 <= CAP) M1 = c1;
      else thr2_1 *= (c1 < TOPK) ? 16.0f : 0.25f;
    }
  }

  // --- Per-gt: exact top-27, IoU, threshold, scatter + worklist append. ---
  for (int q = 0; q < GPB; ++q) {
    const int M = (q == 0) ? M0 : M1;
    const float4 gbox = (q == 0) ? gb0 : gb1;
    const int g = g0 + q;

    // Rank counting over (d, idx) lexicographic keys (order-independent).
    for (int s = tid; s < M; s += 1024) {
      unsigned long long pk_s =
          ((unsigned long long)__float_as_uint(s_d[q][s]) << 20) |
          (unsigned long long)(unsigned)s_i[q][s];
      int rank = 0;
      for (int j = 0; j < M; ++j) {
        unsigned long long pk_j =
            ((unsigned long long)__float_as_uint(s_d[q][j]) << 20) |
            (unsigned long long)(unsigned)s_i[q][j];
        rank += (pk_j < pk_s) ? 1 : 0;
      }
      if (rank < TOPK) s_sel[q][rank] = s_i[q][s];
    }
    __syncthreads();

    if (tid < TOPK) {
      int a = s_sel[q][tid];
      float4 ab = abase[a];
      float area_a = __fmul_rn(ab.z - ab.x, ab.w - ab.y);
      float area_b = __fmul_rn(gbox.z - gbox.x, gbox.w - gbox.y);
      float ltx = fmaxf(ab.x, gbox.x), lty = fmaxf(ab.y, gbox.y);
      float rbx = fminf(ab.z, gbox.z), rby = fminf(ab.w, gbox.w);
      float w = fmaxf(rbx - ltx, 0.0f), h = fmaxf(rby - lty, 0.0f);
      float inter = __fmul_rn(w, h);
      float uni = (area_a + area_b) - inter;
      s_iou[q][tid] = inter / uni;
      float acx = (ab.z + ab.x) * 0.5f, acy = (ab.w + ab.y) * 0.5f;
      float l = acx - gbox.x, t = acy - gbox.y;
      float r = gbox.z - acx, bt = gbox.w - acy;
      float mn = fminf(fminf(l, t), fminf(r, bt));
      s_in[q][tid] = (mn > 0.01f) ? 1 : 0;
    }
    __syncthreads();

    if (tid == 0) {
      float sum = 0.0f;
      for (int k = 0; k < TOPK; ++k) sum += s_iou[q][k];
      float mean = sum / (float)TOPK;
      float vs = 0.0f;
      for (int k = 0; k < TOPK; ++k) {
        float d = s_iou[q][k] - mean;
        vs += __fmul_rn(d, d);
      }
      float sd = __fsqrt_rn(vs / (float)(TOPK - 1));
      s_thresh = mean + sd;
    }
    __syncthreads();

    // Scatter positives into best[] and append to the scatter worklist
    // (wave-aggregated: one atomicAdd per (block,q)).
    if (tid < TOPK) {
      float iou = s_iou[q][tid];
      bool pos = s_in[q][tid] && (iou >= s_thresh);
      if (pos) {
        unsigned long long pk =
            ((unsigned long long)__float_as_uint(iou) << 32) |
            (unsigned long long)(0xFFFFFFFFu - (unsigned)g);
        atomicMax(&best[(size_t)b * N + s_sel[q][tid]], pk);
      }
      unsigned long long mask = __ballot(pos);
      int nact = __popcll(mask);
      int base = 0;
      if (tid == 0 && nact > 0) base = atomicAdd(wl_cnt, nact);
      base = __shfl(base, 0);
      if (pos) {
        int rank = __popcll(mask & ((1ULL << tid) - 1ULL));
        worklist[base + rank] = b * N + s_sel[q][tid];
      }
    }
    __syncthreads(); // s_thresh reused by next q
  }
}

// ---------------------------------------------------------------------------
// Kernel W: fused W1 + token scatter (disjoint outputs; both read-only on
// best after assign).
// Blocks [0,3125): val/idx/matched_gts, one thread per anchor, coalesced.
// Blocks [3125,...): one wave per worklist entry: re-read best[i] (resolved
// winner; duplicates idempotent), copy the 1 KB token row over the fill.
// ---------------------------------------------------------------------------
__global__ __launch_bounds__(256) void atss_write_kernel(
    const unsigned long long* __restrict__ best, // [B*N]
    const float* __restrict__ gts,               // [B,G,4]
    const int* __restrict__ wl_cnt,
    const int* __restrict__ worklist,
    const float* __restrict__ tokens,            // [B,G,T]
    float* __restrict__ out)
{
  const int bid = blockIdx.x;
  const int tid = threadIdx.x;

  if (bid < W1_BLOCKS) {
    float* __restrict__ out_val = out;
    float* __restrict__ out_idx = out + (size_t)BN;
    float* __restrict__ out_mg  = out + (size_t)2 * BN;

    const int i = bid * 256 + tid;
    unsigned long long p = best[i];
    const int b_ = i / N;
    int g = 0;
    float val = NEG_INF_VAL;
    if (p != 0ULL) {
      g   = (int)(0xFFFFFFFFu - (unsigned)(p & 0xFFFFFFFFULL));
      val = __uint_as_float((unsigned)(p >> 32));
    }
    const int row = b_ * G + g; // unmatched -> g=0 (argmax of all -INF)
    out_val[i] = val;
    out_idx[i] = (float)g;
    ((v4f*)out_mg)[i] = ((const v4f*)gts)[row];
    return;
  }

  const int w = (bid - W1_BLOCKS) * 4 + (tid >> 6); // global wave id
  const int lane = tid & 63;
  const int cnt = *wl_cnt;
  if (w >= cnt) return;
  const int i = worklist[w];
  const unsigned long long p = best[i];            // positive -> p != 0
  const int b_ = i / N;
  const int g  = (int)(0xFFFFFFFFu - (unsigned)(p & 0xFFFFFFFFULL));
  v4f t = ((const v4f*)tokens)[(size_t)(b_ * G + g) * 64 + lane];
  ((v4f*)(out + (size_t)6 * BN + (size_t)i * T))[lane] = t;
}

extern "C" void kernel_launch(void* const* d_in, const int* in_sizes, int n_in,
                              void* d_out, int out_size, void* d_ws, size_t ws_size,
                              hipStream_t stream) {
  const float* anchors = (const float*)d_in[0]; // [B,N,4]
  const float* gts     = (const float*)d_in[1]; // [B,G,4]
  const float* tokens  = (const float*)d_in[2]; // [B,G,T]
  float* out = (float*)d_out;

  // Workspace: best (6.4 MB) | wl_cnt (4 B, padded to 64 B) | worklist (64 KB)
  unsigned long long* best = (unsigned long long*)d_ws;
  int* wl_cnt   = (int*)((char*)d_ws + sizeof(unsigned long long) * (size_t)BN);
  int* worklist = wl_cnt + 16;

  atss_zero_kernel<<<512, 256, 0, stream>>>(best, wl_cnt);
  atss_fat_kernel<<<FAT_BLOCKS, 1024, 0, stream>>>(anchors, gts, best,
                                                   wl_cnt, worklist, out);
  atss_write_kernel<<<W1_BLOCKS + SC_BLOCKS, 256, 0, stream>>>(
      best, gts, wl_cnt, worklist, tokens, out);
}